// Round 2
// baseline (617.525 us; speedup 1.0000x reference)
//
#include <hip/hip_runtime.h>

#define D_PIX 16384      // FH*FW
#define NSMP  9
#define TP    64         // pixels per block
#define RS    136        // LDS row stride in shorts (128 ch + 8 pad)

typedef __attribute__((ext_vector_type(8)))  short s16x8;   // 8 bf16 (4 VGPRs) - MFMA A/B frag
typedef __attribute__((ext_vector_type(4)))  float f32x4;
typedef __attribute__((ext_vector_type(16))) float f32x16;  // 32x32 MFMA C/D frag

// RNE fp32->bf16 pair via HW packed convert
__device__ __forceinline__ int cvt2(float lo, float hi) {
    int r;
    asm("v_cvt_pk_bf16_f32 %0, %1, %2" : "=v"(r) : "v"(lo), "v"(hi));
    return r;
}

// LDS column swizzle (in shorts): XOR col bits 3..4 with pixel-tile bits 3..4.
__device__ __forceinline__ int swz(int row, int col) {
    return col ^ (((row >> 3) & 3) << 3);
}

// Block: 256 threads = 4 waves, TP=64 pixels of one batch image.
// Wave w owns heads {2w, 2w+1} = out channels [32w, 32w+32) via 32x32x16 MFMA.
// DEPTH-2 PREFETCH: loads for sample s+2 issued at step s into prA/prB ping-pong;
// stage_write at step s consumes loads issued a full iteration earlier, so the
// compiler's counted vmcnt leaves 8 loads in flight across every barrier and the
// memory queue never drains (kills the per-step vmcnt convoy).
__global__ __launch_bounds__(256, 2)
void deform_attn_kernel(const float* __restrict__ q,
                        const float* __restrict__ kv,
                        const float* __restrict__ Wq,
                        const float* __restrict__ bq,
                        const float* __restrict__ Wk,
                        const float* __restrict__ bk,
                        const float* __restrict__ Wv,
                        const float* __restrict__ bv,
                        float* __restrict__ out)
{
    __shared__ short ldsb[2][TP * RS];   // 2 x 17408 B

    const int tid  = threadIdx.x;
    const int bid  = blockIdx.x;
    const int b    = bid >> 8;            // 256 blocks per batch image
    const int px0  = (bid & 255) * TP;
    const int lane = tid & 63;
    const int w    = tid >> 6;            // wave id 0..3
    const int cl   = lane & 31;           // MFMA col (pixel within 32-tile)
    const int hi   = lane >> 5;           // k-half / row-half select
    const int wch  = w * 32;              // wave's output-channel base (2 heads)

    // ---- staging mapping: thread -> 4 channels x 8 pixels ----
    const int pxb = (tid & 7) * 8;        // pixel base 0..56
    const int chb = (tid >> 3) * 4;       // channel base 0..124
    const int swr = ((tid & 7) & 3) << 3; // write swizzle (row>>3 == tid&7)

    f32x4 prA[4][2], prB[4][2];           // two prefetch buffers (depth-2 pipeline)

    auto stage_load = [&](f32x4 (&pr)[4][2], const float* base, int chstride) {
        #pragma unroll
        for (int j = 0; j < 4; ++j) {
            const float* p = base + (long)(chb + j) * chstride + pxb;
            pr[j][0] = *(const f32x4*)p;
            pr[j][1] = *(const f32x4*)(p + 4);
        }
    };
    auto stage_write = [&](f32x4 (&pr)[4][2], short* buf) {
        #pragma unroll
        for (int i = 0; i < 8; ++i) {
            int2 v;
            v.x = cvt2(pr[0][i >> 2][i & 3], pr[1][i >> 2][i & 3]);
            v.y = cvt2(pr[2][i >> 2][i & 3], pr[3][i >> 2][i & 3]);
            *(int2*)(buf + (pxb + i) * RS + (chb ^ swr)) = v;   // ds_write_b64
        }
    };
    // B frag: B[k = ks*16 + hi*8 + j][px = n*32 + cl], one ds_read_b128
    auto ldb = [&](const short* buf, int n, int ks) -> s16x8 {
        const int row = n * 32 + cl;
        const int col = ks * 16 + hi * 8;
        return *(const s16x8*)(buf + row * RS + swz(row, col));
    };
    // A frag: W[row = wch+cl][k = ks*16 + hi*8 + j], fp32 global -> bf16
    auto ldw = [&](const float* W, int ks) -> s16x8 {
        const float* p = W + (wch + cl) * 128 + ks * 16 + hi * 8;
        f32x4 a = *(const f32x4*)p;
        f32x4 c = *(const f32x4*)(p + 4);
        union { s16x8 v; int i[4]; } u;
        u.i[0] = cvt2(a[0], a[1]); u.i[1] = cvt2(a[2], a[3]);
        u.i[2] = cvt2(c[0], c[1]); u.i[3] = cvt2(c[2], c[3]);
        return u.v;
    };

    // ---- persistent per-wave weight fragments ----
    s16x8 wkF[8], wvF[8];
    #pragma unroll
    for (int ks = 0; ks < 8; ++ks) { wkF[ks] = ldw(Wk, ks); wvF[ks] = ldw(Wv, ks); }

    float qp[2][16];      // q projection (C/D layout), [ntile][reg]
    float oacc[2][16];    // output accumulator (bv folded to epilogue)
    float ls[2][2];       // softmax denominator [ntile][head]
    float qb4[2][2];      // (qp . bk) * SCALE   [ntile][head]

    const float* qbase  = q  + (long)(b * 128) * D_PIX + px0;
    const float* kvbase = kv + (long)(b * 128) * NSMP * D_PIX + px0;

    // ---- prologue: stage q tile, compute qp + qb, prefetch samples 0 and 1 ----
    stage_load(prA, qbase, D_PIX);
    stage_write(prA, ldsb[0]);
    __syncthreads();

    stage_load(prA, kvbase, NSMP * D_PIX);                 // sample 0
    stage_load(prB, kvbase + D_PIX, NSMP * D_PIX);         // sample 1
    {
        float bkv[16], bqv[16];
        #pragma unroll
        for (int r = 0; r < 16; ++r) {
            const int o = wch + (r & 3) + 8 * (r >> 2) + 4 * hi;
            bkv[r] = bk[o];
            bqv[r] = bq[o];
        }
        s16x8 wqF[8];
        #pragma unroll
        for (int ks = 0; ks < 8; ++ks) wqF[ks] = ldw(Wq, ks);
        #pragma unroll
        for (int n = 0; n < 2; ++n) {
            f32x16 acc;
            #pragma unroll
            for (int r = 0; r < 16; ++r) acc[r] = 0.f;
            #pragma unroll
            for (int ks = 0; ks < 8; ++ks)
                acc = __builtin_amdgcn_mfma_f32_32x32x16_bf16(wqF[ks], ldb(ldsb[0], n, ks), acc, 0, 0, 0);
            float t0 = 0.f, t1 = 0.f;
            #pragma unroll
            for (int r = 0; r < 16; ++r) {
                const float v = acc[r] + bqv[r];
                qp[n][r] = v;
                if (r < 8) t0 += v * bkv[r]; else t1 += v * bkv[r];
            }
            t0 += __shfl_xor(t0, 32);
            t1 += __shfl_xor(t1, 32);
            qb4[n][0] = t0 * 0.25f;       // SCALE = 16^-0.5
            qb4[n][1] = t1 * 0.25f;
            ls[n][0] = ls[n][1] = 0.f;
            #pragma unroll
            for (int r = 0; r < 16; ++r) oacc[n][r] = 0.f;
        }
    }
    stage_write(prA, ldsb[1]);            // sample 0 -> LDS (prA free after)
    __syncthreads();

    // ---- main loop over 9 samples (fully unrolled: static prA/prB ping-pong) ----
    // invariant at top of step s: sample s in ldsb[(s+1)&1];
    //   pref(s odd ? prA : prB) holds sample s+1; other buffer free.
    #pragma unroll
    for (int s = 0; s < NSMP; ++s) {
        if (s + 2 < NSMP) {               // issue loads for s+2 (stay in flight all step)
            if (s & 1) stage_load(prB, kvbase + (long)(s + 2) * D_PIX, NSMP * D_PIX);
            else       stage_load(prA, kvbase + (long)(s + 2) * D_PIX, NSMP * D_PIX);
        }
        const short* buf = ldsb[(s + 1) & 1];
        #pragma unroll
        for (int n = 0; n < 2; ++n) {
            f32x16 kacc, vacc;
            #pragma unroll
            for (int r = 0; r < 16; ++r) { kacc[r] = 0.f; vacc[r] = 0.f; }
            #pragma unroll
            for (int ks = 0; ks < 8; ++ks) {
                const s16x8 bfr = ldb(buf, n, ks);
                kacc = __builtin_amdgcn_mfma_f32_32x32x16_bf16(wkF[ks], bfr, kacc, 0, 0, 0);
                vacc = __builtin_amdgcn_mfma_f32_32x32x16_bf16(wvF[ks], bfr, vacc, 0, 0, 0);
            }
            float p0 = 0.f, p1 = 0.f;
            #pragma unroll
            for (int r = 0; r < 8; ++r)  p0 += qp[n][r] * kacc[r];
            #pragma unroll
            for (int r = 8; r < 16; ++r) p1 += qp[n][r] * kacc[r];
            p0 += __shfl_xor(p0, 32);
            p1 += __shfl_xor(p1, 32);
            const float e0 = __expf(fmaf(p0, 0.25f, qb4[n][0]));
            const float e1 = __expf(fmaf(p1, 0.25f, qb4[n][1]));
            ls[n][0] += e0;
            ls[n][1] += e1;
            #pragma unroll
            for (int r = 0; r < 8; ++r)  oacc[n][r] += e0 * vacc[r];
            #pragma unroll
            for (int r = 8; r < 16; ++r) oacc[n][r] += e1 * vacc[r];
        }
        if (s + 1 < NSMP) {               // write sample s+1 (loaded one full step ago:
                                          // counted vmcnt leaves this step's loads in flight)
            if (s & 1) stage_write(prA, ldsb[s & 1]);
            else       stage_write(prB, ldsb[s & 1]);
        }
        __syncthreads();
    }

    // ---- epilogue: divide by denom, add folded bv, store fp32 ----
    #pragma unroll
    for (int n = 0; n < 2; ++n) {
        const float i0 = 1.f / ls[n][0];
        const float i1 = 1.f / ls[n][1];
        #pragma unroll
        for (int r = 0; r < 16; ++r) {
            const int o = wch + (r & 3) + 8 * (r >> 2) + 4 * hi;
            out[(long)(b * 128 + o) * D_PIX + px0 + n * 32 + cl] =
                oacc[n][r] * (r < 8 ? i0 : i1) + bv[o];
        }
    }
}

extern "C" void kernel_launch(void* const* d_in, const int* in_sizes, int n_in,
                              void* d_out, int out_size, void* d_ws, size_t ws_size,
                              hipStream_t stream) {
    const float* q  = (const float*)d_in[0];
    const float* kv = (const float*)d_in[1];
    const float* Wq = (const float*)d_in[2];
    const float* bq = (const float*)d_in[3];
    const float* Wk = (const float*)d_in[4];
    const float* bk = (const float*)d_in[5];
    const float* Wv = (const float*)d_in[6];
    const float* bv = (const float*)d_in[7];
    float* out = (float*)d_out;

    dim3 grid(1024);   // 4 batches * (16384/64) pixel tiles
    dim3 block(256);
    hipLaunchKernelGGL(deform_attn_kernel, grid, block, 0, stream,
                       q, kv, Wq, bq, Wk, bk, Wv, bv, out);
}

// Round 5
// 451.458 us; speedup vs baseline: 1.3678x; 1.3678x over previous
//
#include <hip/hip_runtime.h>

#define D_PIX 16384              // FH*FW
#define NSMP  9
#define TP    64                 // pixels per block
#define RS    136                // bf16 tile row stride in shorts (128 ch + 8 pad)
#define CHS_KV ((long)NSMP * D_PIX)

typedef __attribute__((ext_vector_type(8)))  short s16x8;   // 8 bf16 - MFMA A/B frag
typedef __attribute__((ext_vector_type(4)))  float f32x4;
typedef __attribute__((ext_vector_type(16))) float f32x16;  // 32x32 MFMA C/D frag

// RNE fp32->bf16 pair via HW packed convert
__device__ __forceinline__ int cvt2(float lo, float hi) {
    int r;
    asm("v_cvt_pk_bf16_f32 %0, %1, %2" : "=v"(r) : "v"(lo), "v"(hi));
    return r;
}
// bf16-tile column swizzle (in shorts)
__device__ __forceinline__ int swz(int row, int col) {
    return col ^ (((row >> 3) & 3) << 3);
}
// async global->LDS DMA, 16B/lane, dest = wave-uniform base + lane*16
__device__ __forceinline__ void gl16(const float* g, float* l) {
    __builtin_amdgcn_global_load_lds((const __attribute__((address_space(1))) void*)g,
                                     (__attribute__((address_space(3))) void*)l, 16, 0, 0);
}

#define WAIT_VM0   asm volatile("s_waitcnt vmcnt(0)" ::: "memory")
#define WAIT_LGKM0 asm volatile("s_waitcnt lgkmcnt(0)" ::: "memory")
#define SBAR       __builtin_amdgcn_s_barrier()
#define SFENCE     __builtin_amdgcn_sched_barrier(0)

// Block: 256 threads = 4 waves, TP=64 pixels of one batch image.
// Wave w owns heads {2w,2w+1} = out-ch [32w,32w+32) via 32x32x16 MFMA.
// Staging: global_load_lds DMA (zero VGPR) -> f32 LDS [ch][64px]. Wave w's DMA
// covers exactly ch [32w,32w+32) and only wave w conv-reads those rows: the f32
// buffer is wave-private, so the per-wave in-order vmcnt(0) suffices (no barrier).
// Raw s_barrier + lgkmcnt(0) only (vmcnt is NEVER drained at a barrier): the DMA
// for sample s+1, issued mid-step s, stays in flight across both barriers and
// the whole compute phase -- the memory queue never empties.
// RACE FIX (r4): lgkmcnt(0) between conv()'s fstg reads and the DMA issue that
// overwrites the same fstg rows -- DMA LDS-writes return via the VMEM path with
// no ordering vs queued DS reads, so the reads must retire first.
// Barrier count is uniform across waves (2 prologue + 18 loop).
__global__ __launch_bounds__(256, 2)
void deform_attn_kernel(const float* __restrict__ q,
                        const float* __restrict__ kv,
                        const float* __restrict__ Wq,
                        const float* __restrict__ bq,
                        const float* __restrict__ Wk,
                        const float* __restrict__ bk,
                        const float* __restrict__ Wv,
                        const float* __restrict__ bv,
                        float* __restrict__ out)
{
    __shared__ float fstg[128 * 64];     // 32 KB f32 staging, [ch][px], wave-private rows
    __shared__ short bt[TP * RS];        // 17408 B bf16 tile [px][ch^swz]

    const int tid  = threadIdx.x;
    const int bid  = blockIdx.x;
    const int b    = bid >> 8;            // 256 blocks per batch image
    const int px0  = (bid & 255) * TP;
    const int lane = tid & 63;
    const int w    = tid >> 6;            // wave id 0..3 (wave-uniform)
    const int cl   = lane & 31;           // MFMA col (pixel within 32-tile)
    const int hi   = lane >> 5;           // k-half / row-half select
    const int wch  = w * 32;              // wave's output-channel base (2 heads)

    // DMA lane decomposition: instr i of wave w covers ch [w*32+i*4, +4), 16 px-groups
    const int glch = lane >> 4;           // 0..3: channel within 4-ch group
    const int glpg = lane & 15;           // px group (4 px = 16 B)

    // conv-pass mapping: thread -> 4 channels x 8 pixels (wave-own ch range)
    const int pxb = (tid & 7) * 8;        // pixel base 0..56
    const int chb = (tid >> 3) * 4;       // channel base: wave w -> [32w, 32w+28]
    const int swr = ((tid & 7) & 3) << 3; // bf16 write swizzle (row>>3 == tid&7)

    auto stage_gl = [&](const float* src, long chstride) {
        #pragma unroll
        for (int i = 0; i < 8; ++i) {
            const int chB = wch + i * 4;                     // wave-uniform
            gl16(src + (long)(chB + glch) * chstride + glpg * 4,
                 fstg + chB * 64);                           // linear LDS dest
        }
    };
    // f32 LDS -> cvt -> swizzled bf16 tile (own rows only)
    auto conv = [&]() {
        f32x4 pr[4][2];
        #pragma unroll
        for (int j = 0; j < 4; ++j) {
            const float* p = fstg + (chb + j) * 64 + pxb;
            pr[j][0] = *(const f32x4*)p;                     // ds_read_b128
            pr[j][1] = *(const f32x4*)(p + 4);
        }
        #pragma unroll
        for (int i = 0; i < 8; ++i) {
            int2 v;
            v.x = cvt2(pr[0][i >> 2][i & 3], pr[1][i >> 2][i & 3]);
            v.y = cvt2(pr[2][i >> 2][i & 3], pr[3][i >> 2][i & 3]);
            *(int2*)(bt + (pxb + i) * RS + (chb ^ swr)) = v; // ds_write_b64
        }
    };
    // B frag: B[k = ks*16 + hi*8 + j][px = n*32 + cl], one ds_read_b128
    auto ldb = [&](int n, int ks) -> s16x8 {
        const int row = n * 32 + cl;
        const int col = ks * 16 + hi * 8;
        return *(const s16x8*)(bt + row * RS + swz(row, col));
    };
    // A frag: W[row = wch+cl][k = ks*16 + hi*8 + j], fp32 global -> bf16
    auto ldw = [&](const float* W, int ks) -> s16x8 {
        const float* p = W + (wch + cl) * 128 + ks * 16 + hi * 8;
        f32x4 a = *(const f32x4*)p;
        f32x4 c = *(const f32x4*)(p + 4);
        union { s16x8 v; int i[4]; } u;
        u.i[0] = cvt2(a[0], a[1]); u.i[1] = cvt2(a[2], a[3]);
        u.i[2] = cvt2(c[0], c[1]); u.i[3] = cvt2(c[2], c[3]);
        return u.v;
    };

    const float* qbase  = q  + (long)(b * 128) * D_PIX + px0;
    const float* kvbase = kv + (long)(b * 128) * CHS_KV + px0;   // + ch*CHS_KV + s*D_PIX

    // ---- prologue: DMA q tile; weights -> regs meanwhile ----
    stage_gl(qbase, D_PIX);

    s16x8 wkF[8], wvF[8];
    #pragma unroll
    for (int ks = 0; ks < 8; ++ks) { wkF[ks] = ldw(Wk, ks); wvF[ks] = ldw(Wv, ks); }

    float qp[2][16];      // q projection (C/D layout)
    float oacc[2][16];    // output accumulator (bv folded to epilogue)
    float ls[2][2];       // softmax denominator [ntile][head]
    float qb4[2][2];      // (qp . bk) * SCALE   [ntile][head]

    WAIT_VM0; SFENCE;     // q DMA landed (weight loads also drained; once, harmless)
    conv();               // q -> bt
    WAIT_LGKM0; SFENCE;   // conv's fstg reads retired before fstg is re-targeted
    stage_gl(kvbase, CHS_KV);          // sample 0 DMA, in flight during qp compute
    SFENCE;
    SBAR; SFENCE;                      // q bf16 tile visible block-wide (lgkm already 0)

    {
        float bkv[16], bqv[16];
        #pragma unroll
        for (int r = 0; r < 16; ++r) {
            const int o = wch + (r & 3) + 8 * (r >> 2) + 4 * hi;
            bkv[r] = bk[o];
            bqv[r] = bq[o];
        }
        s16x8 wqF[8];
        #pragma unroll
        for (int ks = 0; ks < 8; ++ks) wqF[ks] = ldw(Wq, ks);
        #pragma unroll
        for (int n = 0; n < 2; ++n) {
            f32x16 acc;
            #pragma unroll
            for (int r = 0; r < 16; ++r) acc[r] = 0.f;
            #pragma unroll
            for (int ks = 0; ks < 8; ++ks)
                acc = __builtin_amdgcn_mfma_f32_32x32x16_bf16(wqF[ks], ldb(n, ks), acc, 0, 0, 0);
            float t0 = 0.f, t1 = 0.f;
            #pragma unroll
            for (int r = 0; r < 16; ++r) {
                const float v = acc[r] + bqv[r];
                qp[n][r] = v;
                if (r < 8) t0 += v * bkv[r]; else t1 += v * bkv[r];
            }
            t0 += __shfl_xor(t0, 32);
            t1 += __shfl_xor(t1, 32);
            qb4[n][0] = t0 * 0.25f;       // SCALE = 16^-0.5
            qb4[n][1] = t1 * 0.25f;
            ls[n][0] = ls[n][1] = 0.f;
            #pragma unroll
            for (int r = 0; r < 16; ++r) oacc[n][r] = 0.f;
        }
    }
    WAIT_LGKM0; SBAR; SFENCE;          // all waves done reading q tile

    // ---- main loop over 9 samples (single bf16 tile, 2 raw barriers/step) ----
    for (int s = 0; s < NSMP; ++s) {
        WAIT_VM0; SFENCE;              // own DMA rows for sample s landed
        conv();                        // fstg -> bt
        WAIT_LGKM0; SFENCE;            // conv's fstg reads retired (race fix)
        if (s + 1 < NSMP)              // DMA s+1: in flight across both barriers + compute
            stage_gl(kvbase + (long)(s + 1) * D_PIX, CHS_KV);
        SFENCE;
        SBAR; SFENCE;                  // bt visible block-wide (lgkm 0; vmcnt NOT drained)

        #pragma unroll
        for (int n = 0; n < 2; ++n) {
            f32x16 kacc, vacc;
            #pragma unroll
            for (int r = 0; r < 16; ++r) { kacc[r] = 0.f; vacc[r] = 0.f; }
            #pragma unroll
            for (int ks = 0; ks < 8; ++ks) {
                const s16x8 bfr = ldb(n, ks);
                kacc = __builtin_amdgcn_mfma_f32_32x32x16_bf16(wkF[ks], bfr, kacc, 0, 0, 0);
                vacc = __builtin_amdgcn_mfma_f32_32x32x16_bf16(wvF[ks], bfr, vacc, 0, 0, 0);
            }
            float p0 = 0.f, p1 = 0.f;
            #pragma unroll
            for (int r = 0; r < 8; ++r)  p0 += qp[n][r] * kacc[r];
            #pragma unroll
            for (int r = 8; r < 16; ++r) p1 += qp[n][r] * kacc[r];
            p0 += __shfl_xor(p0, 32);
            p1 += __shfl_xor(p1, 32);
            const float e0 = __expf(fmaf(p0, 0.25f, qb4[n][0]));
            const float e1 = __expf(fmaf(p1, 0.25f, qb4[n][1]));
            ls[n][0] += e0;
            ls[n][1] += e1;
            #pragma unroll
            for (int r = 0; r < 8; ++r)  oacc[n][r] += e0 * vacc[r];
            #pragma unroll
            for (int r = 8; r < 16; ++r) oacc[n][r] += e1 * vacc[r];
        }
        WAIT_LGKM0; SBAR; SFENCE;      // all waves done reading bt before next conv
    }

    // ---- epilogue: divide by denom, add folded bv, store fp32 ----
    #pragma unroll
    for (int n = 0; n < 2; ++n) {
        const float i0 = 1.f / ls[n][0];
        const float i1 = 1.f / ls[n][1];
        #pragma unroll
        for (int r = 0; r < 16; ++r) {
            const int o = wch + (r & 3) + 8 * (r >> 2) + 4 * hi;
            out[(long)(b * 128 + o) * D_PIX + px0 + n * 32 + cl] =
                oacc[n][r] * (r < 8 ? i0 : i1) + bv[o];
        }
    }
}

extern "C" void kernel_launch(void* const* d_in, const int* in_sizes, int n_in,
                              void* d_out, int out_size, void* d_ws, size_t ws_size,
                              hipStream_t stream) {
    const float* q  = (const float*)d_in[0];
    const float* kv = (const float*)d_in[1];
    const float* Wq = (const float*)d_in[2];
    const float* bq = (const float*)d_in[3];
    const float* Wk = (const float*)d_in[4];
    const float* bk = (const float*)d_in[5];
    const float* Wv = (const float*)d_in[6];
    const float* bv = (const float*)d_in[7];
    float* out = (float*)d_out;

    dim3 grid(1024);   // 4 batches * (16384/64) pixel tiles
    dim3 block(256);
    hipLaunchKernelGGL(deform_attn_kernel, grid, block, 0, stream,
                       q, kv, Wq, bq, Wk, bk, Wv, bv, out);
}